// Round 7
// baseline (191.029 us; speedup 1.0000x reference)
//
#include <hip/hip_runtime.h>
#include <hip/hip_bf16.h>
#include <math.h>

// Problem constants: x [8,256,64,64] fp32, N = 4096, C = 256, Cqk = 32.
#define B_   8
#define C_   256
#define N_   4096
// 1/sqrt(32) * log2(e): scores computed directly in log2 space -> exp2 only.
#define QSCALE_L2E 0.2550541451582815f
#define DEFER_THR  11.5f   // defer-max threshold in log2 units (~8 nats)

typedef __attribute__((ext_vector_type(8))) short bf16x8;   // 8 bf16 = 4 VGPRs
typedef __attribute__((ext_vector_type(4))) float f32x4;

__device__ __forceinline__ unsigned short bfu(float f) {
    __hip_bfloat16 h = __float2bfloat16(f);
    return __builtin_bit_cast(unsigned short, h);
}
// v_cvt_pk_bf16_f32: lo -> D[15:0], hi -> D[31:16] (single VALU op)
__device__ __forceinline__ unsigned cvtpk(float lo, float hi) {
    unsigned r;
    asm("v_cvt_pk_bf16_f32 %0, %1, %2" : "=v"(r) : "v"(lo), "v"(hi));
    return r;
}

// ---------------------------------------------------------------------------
// Kernel 0: one-time W -> bf16 prep. wbf layout: Wq[32*256] | Wk | Wv[256*256].
// ---------------------------------------------------------------------------
__global__ __launch_bounds__(256) void w_prep(
    const float* __restrict__ Wq, const float* __restrict__ Wk,
    const float* __restrict__ Wv, unsigned short* __restrict__ wbf)
{
    const int i = blockIdx.x * 256 + threadIdx.x;
    const int off = i * 4;
    float4 f;
    if (off < 32 * C_)            f = *reinterpret_cast<const float4*>(Wq + off);
    else if (off < 64 * C_)       f = *reinterpret_cast<const float4*>(Wk + off - 32 * C_);
    else                          f = *reinterpret_cast<const float4*>(Wv + off - 64 * C_);
    ushort4 u;
    u.x = bfu(f.x); u.y = bfu(f.y); u.z = bfu(f.z); u.w = bfu(f.w);
    *reinterpret_cast<ushort4*>(wbf + off) = u;
}

// ---------------------------------------------------------------------------
// Kernel 1: QKV projection via MFMA (unchanged from round 6).
// Outputs: q,k [b][n][32] bf16 (q pre-scaled by QSCALE_L2E), v [b][c][n] bf16.
// ---------------------------------------------------------------------------
__global__ __launch_bounds__(256, 2) void qkv_proj_mfma(
    const float* __restrict__ x, const unsigned short* __restrict__ wbf,
    const float* __restrict__ bq, const float* __restrict__ bk,
    const float* __restrict__ bv,
    unsigned short* __restrict__ q, unsigned short* __restrict__ k,
    unsigned short* __restrict__ v)
{
    const int b = blockIdx.y, n0 = blockIdx.x * 64;
    const int t = threadIdx.x;
    const int w = t >> 6, l = t & 63;
    const int li = l & 15, g = l >> 4;

    __shared__ unsigned short xT[64 * 256];     // 32 KB; reused as vS[256][64]
    __shared__ unsigned short qkS[2 * 64 * 32]; // 8 KB

    {
        const int n = t & 63;
        const int cq0 = t >> 6;
        const float* xb = x + ((size_t)b * C_) * N_ + n0 + n;
        #pragma unroll 4
        for (int s = 0; s < 16; ++s) {
            const int cq = cq0 + 4 * s;
            const float f0 = xb[(size_t)(cq * 4 + 0) * N_];
            const float f1 = xb[(size_t)(cq * 4 + 1) * N_];
            const float f2 = xb[(size_t)(cq * 4 + 2) * N_];
            const float f3 = xb[(size_t)(cq * 4 + 3) * N_];
            ushort4 pk;
            pk.x = bfu(f0); pk.y = bfu(f1); pk.z = bfu(f2); pk.w = bfu(f3);
            const int byte = n * 512 + (((cq >> 1) ^ (n & 7)) << 4) + (cq & 1) * 8;
            *reinterpret_cast<ushort4*>(reinterpret_cast<char*>(xT) + byte) = pk;
        }
    }
    __syncthreads();

    const unsigned short* wq_bf = wbf;
    const unsigned short* wk_bf = wbf + 32 * C_;
    const unsigned short* wv_bf = wbf + 64 * C_;

    const unsigned short* wqk_bf = (w < 2) ? wq_bf : wk_bf;
    const float* bqk = (w < 2) ? bq : bk;
    const float qscl = (w < 2) ? QSCALE_L2E : 1.0f;
    const int mt0 = (w & 1) * 2;
    const int ov0 = w * 64;

    f32x4 accv[4][4];
    f32x4 accq[2][2];
    const f32x4 z4 = {0.f, 0.f, 0.f, 0.f};
    #pragma unroll
    for (int a = 0; a < 4; ++a)
        #pragma unroll
        for (int c2 = 0; c2 < 4; ++c2) accv[a][c2] = z4;
    #pragma unroll
    for (int a = 0; a < 2; ++a)
        #pragma unroll
        for (int c2 = 0; c2 < 2; ++c2) accq[a][c2] = z4;

    #pragma unroll 2
    for (int kk = 0; kk < 8; ++kk) {
        bf16x8 xf[4];
        #pragma unroll
        for (int nt = 0; nt < 4; ++nt) {
            const int row = nt * 16 + li;
            const int byte = row * 512 + (((kk * 4 + g) ^ (row & 7)) << 4);
            xf[nt] = *reinterpret_cast<const bf16x8*>(
                reinterpret_cast<const char*>(xT) + byte);
        }
        #pragma unroll
        for (int ot = 0; ot < 4; ++ot) {
            const bf16x8 wV = *reinterpret_cast<const bf16x8*>(
                wv_bf + (size_t)(ov0 + ot * 16 + li) * C_ + kk * 32 + g * 8);
            #pragma unroll
            for (int nt = 0; nt < 4; ++nt)
                accv[nt][ot] = __builtin_amdgcn_mfma_f32_16x16x32_bf16(
                    xf[nt], wV, accv[nt][ot], 0, 0, 0);
        }
        #pragma unroll
        for (int ot = 0; ot < 2; ++ot) {
            const bf16x8 wA = *reinterpret_cast<const bf16x8*>(
                wqk_bf + (size_t)(ot * 16 + li) * C_ + kk * 32 + g * 8);
            #pragma unroll
            for (int m2 = 0; m2 < 2; ++m2)
                accq[ot][m2] = __builtin_amdgcn_mfma_f32_16x16x32_bf16(
                    wA, xf[mt0 + m2], accq[ot][m2], 0, 0, 0);
        }
    }

    __syncthreads();   // xT reads done: reuse as vS

    {
        const int qk = (w < 2) ? 0 : 1;
        #pragma unroll
        for (int ot = 0; ot < 2; ++ot) {
            const int d0 = ot * 16 + 4 * g;
            const float4 b4 = *reinterpret_cast<const float4*>(bqk + d0);
            const int slot = ot * 4 + g;
            #pragma unroll
            for (int m2 = 0; m2 < 2; ++m2) {
                const int n = (mt0 + m2) * 16 + li;
                ushort4 s4;
                s4.x = bfu((accq[ot][m2][0] + b4.x) * qscl);
                s4.y = bfu((accq[ot][m2][1] + b4.y) * qscl);
                s4.z = bfu((accq[ot][m2][2] + b4.z) * qscl);
                s4.w = bfu((accq[ot][m2][3] + b4.w) * qscl);
                const int byte = qk * 4096 + n * 64 + ((slot ^ (n & 7)) << 3);
                *reinterpret_cast<ushort4*>(reinterpret_cast<char*>(qkS) + byte) = s4;
            }
        }
    }
    {
        #pragma unroll
        for (int ot = 0; ot < 4; ++ot) {
            const int o = ov0 + ot * 16 + li;
            const float bias = bv[o];
            #pragma unroll
            for (int nt = 0; nt < 4; ++nt) {
                ushort4 s4;
                s4.x = bfu(accv[nt][ot][0] + bias);
                s4.y = bfu(accv[nt][ot][1] + bias);
                s4.z = bfu(accv[nt][ot][2] + bias);
                s4.w = bfu(accv[nt][ot][3] + bias);
                const int slot = nt * 4 + g;
                const int byte = o * 128 + ((slot ^ (o & 7)) << 3);
                *reinterpret_cast<ushort4*>(reinterpret_cast<char*>(xT) + byte) = s4;
            }
        }
    }
    __syncthreads();

    {
        const char* qks = reinterpret_cast<const char*>(qkS);
        #pragma unroll
        for (int qk = 0; qk < 2; ++qk) {
            const int n = t >> 2, s2 = (t & 3) * 2;
            const int byteA = qk * 4096 + n * 64 + (((s2    ) ^ (n & 7)) << 3);
            const int byteB = qk * 4096 + n * 64 + (((s2 + 1) ^ (n & 7)) << 3);
            const uint2 lo = *reinterpret_cast<const uint2*>(qks + byteA);
            const uint2 hi = *reinterpret_cast<const uint2*>(qks + byteB);
            uint4 val = make_uint4(lo.x, lo.y, hi.x, hi.y);
            unsigned short* dst = (qk == 0) ? q : k;
            *reinterpret_cast<uint4*>(dst + ((size_t)b * N_ + n0) * 32 + t * 8) = val;
        }
    }
    {
        const char* vs = reinterpret_cast<const char*>(xT);
        #pragma unroll
        for (int p2 = 0; p2 < 8; ++p2) {
            const int o = p2 * 32 + (t >> 3);
            const int s2 = (t & 7) * 2;
            const int byteA = o * 128 + (((s2    ) ^ (o & 7)) << 3);
            const int byteB = o * 128 + (((s2 + 1) ^ (o & 7)) << 3);
            const uint2 lo = *reinterpret_cast<const uint2*>(vs + byteA);
            const uint2 hi = *reinterpret_cast<const uint2*>(vs + byteB);
            uint4 val = make_uint4(lo.x, lo.y, hi.x, hi.y);
            *reinterpret_cast<uint4*>(v + ((size_t)b * C_ + o) * N_ + n0 + (t & 7) * 8) = val;
        }
    }
}

// ---------------------------------------------------------------------------
// Kernel 2: flash attention, 8 waves (512 thr), 2-D wave split for occupancy:
// wave w: QK+softmax for (qslice = w&3 [16 i], jhalf = w>>2 [64 j]) and PV for
// c-slice [w*32, +32) over the FULL 128 j. Cross-half max exchanged via LDS
// each iter (both halves share one m -> l additive, no output combine).
// 2 barriers/iter; kT/pS/mx/f all single-buffered (reads sit before the
// barrier that precedes their overwrite). V loads lead use by one full iter
// (counted vmcnt(1)/vmcnt(8), never an early drain). 2 blocks/CU = 16
// waves/CU (4/SIMD) -- needs VGPR <= 128, hence launch_bounds(512, 4).
// ---------------------------------------------------------------------------
__global__ __launch_bounds__(512, 4) void attn_mfma(
    const unsigned short* __restrict__ q, const unsigned short* __restrict__ k,
    const unsigned short* __restrict__ v,
    const float* __restrict__ x, const float* __restrict__ gamma,
    float* __restrict__ out)
{
    const int id = blockIdx.x;
    const int b = id & 7;                 // batch == XCD
    const int i0 = (id >> 3) * 64;
    const int t = threadIdx.x;
    const int w = t >> 6, l = t & 63;
    const int li = l & 15, g = l >> 4;
    const int QS = w & 3;                 // qslice (16 queries)
    const int JH = w >> 2;                // j-half (64 of 128 j)
    const int cw0 = w * 32;               // PV c-slice base

    __shared__ unsigned short kT[128 * 32];      // 8 KB K tile (single buffer)
    __shared__ unsigned short pS[4][4][64 * 8];  // 16 KB P frags [qslice][kt]
    __shared__ float mx_s[4][2][16];             // per-iter tile max [qs][jh][i]
    __shared__ float f_s[4][16];
    __shared__ int   flag_s[4];
    __shared__ float l_s[4][2][16];

    const unsigned short* qb = q + (size_t)b * N_ * 32;
    const unsigned short* kb = k + (size_t)b * N_ * 32;
    const unsigned short* vb = v + ((size_t)b * C_) * N_;

    // Q B-frag for own qslice: i = i0 + QS*16 + li
    const bf16x8 qf = *reinterpret_cast<const bf16x8*>(
        qb + (size_t)(i0 + QS * 16 + li) * 32 + g * 8);

    f32x4 acc[2][4];   // [ct][it] : O^T[c][i], c-slice 32 wide
    const f32x4 z4 = {0.f, 0.f, 0.f, 0.f};
    #pragma unroll
    for (int a = 0; a < 2; ++a)
        #pragma unroll
        for (int c2 = 0; c2 < 4; ++c2) acc[a][c2] = z4;

    float m_run = -3.0e38f;
    float l_part = 0.f;

    // K staging: 512 threads x 1 dwordx4 = 128x32 tile. Rows permuted per
    // 64-row half so S^T D-frag (jt,g,r) is j_local = (jt>>1)*32+(jt&1)*4+8g+r.
    const int tt = t & 255, hh = t >> 8;
    const int jr = tt >> 2, sl = tt & 3;
    const int jt_s = jr >> 4, gg = (jr >> 2) & 3, rr = jr & 3;
    const int jloc = (jt_s >> 1) * 32 + (jt_s & 1) * 4 + gg * 8 + rr;
    const int s_src = sl ^ (jr & 3);
    const int kvoff_sh = (hh * 64 + jloc) * 32 + s_src * 8;
    const unsigned voffK = (unsigned)(kvoff_sh * 2);
    unsigned short* kdst = &kT[hh * 2048 + tt * 8];

    // V voffsets (bytes), loop-invariant
    unsigned voffV[2][4];
    #pragma unroll
    for (int ct = 0; ct < 2; ++ct)
        #pragma unroll
        for (int kt = 0; kt < 4; ++kt)
            voffV[ct][kt] = (unsigned)(((cw0 + ct * 16 + li) * N_ + kt * 32 + g * 8) * 2);

    union PB { unsigned wo[4]; bf16x8 v8; };

    bf16x8 knx;
    bf16x8 vA[2][4];

    // QK(jj) for own (QS, JH): 4 MFMA -> sT; publish per-i tile max to mx_s
    auto qk_and_max = [&](f32x4* sT) {
        const char* kbuf = reinterpret_cast<const char*>(&kT[0]) + JH * 4096;
        #pragma unroll
        for (int jt = 0; jt < 4; ++jt) {
            const int row = jt * 16 + li;
            const bf16x8 kA = *reinterpret_cast<const bf16x8*>(
                kbuf + row * 64 + ((g ^ (row & 3)) << 4));
            sT[jt] = __builtin_amdgcn_mfma_f32_16x16x32_bf16(kA, qf, z4, 0, 0, 0);
        }
        float fm0 = fmaxf(fmaxf(sT[0][0], sT[0][1]), fmaxf(sT[0][2], sT[0][3]));
        float fm1 = fmaxf(fmaxf(sT[1][0], sT[1][1]), fmaxf(sT[1][2], sT[1][3]));
        float fm2 = fmaxf(fmaxf(sT[2][0], sT[2][1]), fmaxf(sT[2][2], sT[2][3]));
        float fm3 = fmaxf(fmaxf(sT[3][0], sT[3][1]), fmaxf(sT[3][2], sT[3][3]));
        float mx = fmaxf(fmaxf(fm0, fm1), fmaxf(fm2, fm3));
        mx = fmaxf(mx, __shfl_xor(mx, 16));   // reduce across g (same li)
        mx = fmaxf(mx, __shfl_xor(mx, 32));
        if (l < 16) mx_s[QS][JH][li] = mx;
    };

    // softmax finish after the mx barrier: one consistent m across halves
    auto sm_finish_publish = [&](f32x4* sT) {
        const float cand = fmaxf(mx_s[QS][0][li], mx_s[QS][1][li]);
        float f = 1.0f;
        const int any = __any(cand > m_run + DEFER_THR) ? 1 : 0;
        if (any) {
            const float mnew = fmaxf(m_run, cand);
            f = __builtin_amdgcn_exp2f(m_run - mnew);
            m_run = mnew;
            l_part *= f;
        }
        #pragma unroll
        for (int jt = 0; jt < 4; ++jt)
            #pragma unroll
            for (int r = 0; r < 4; ++r)
                sT[jt][r] = __builtin_amdgcn_exp2f(sT[jt][r] - m_run);
        const f32x4 sv = (sT[0] + sT[1]) + (sT[2] + sT[3]);
        l_part += (sv[0] + sv[1]) + (sv[2] + sv[3]);
        #pragma unroll
        for (int kt2 = 0; kt2 < 2; ++kt2) {   // global kt = JH*2 + kt2
            PB pk2;
            pk2.wo[0] = cvtpk(sT[2 * kt2][0],     sT[2 * kt2][1]);
            pk2.wo[1] = cvtpk(sT[2 * kt2][2],     sT[2 * kt2][3]);
            pk2.wo[2] = cvtpk(sT[2 * kt2 + 1][0], sT[2 * kt2 + 1][1]);
            pk2.wo[3] = cvtpk(sT[2 * kt2 + 1][2], sT[2 * kt2 + 1][3]);
            *reinterpret_cast<bf16x8*>(&pS[QS][JH * 2 + kt2][l * 8]) = pk2.v8;
        }
        if (JH == 0) {
            if (l < 16) f_s[QS][li] = f;
            if (l == 0) flag_s[QS] = any;
        }
    };

    // ---- prologue: stage K(0) ----
    {
        const bf16x8 a0 = *reinterpret_cast<const bf16x8*>(kb + kvoff_sh);
        *reinterpret_cast<bf16x8*>(kdst) = a0;
    }
    __syncthreads();

    // ---- peel jj = 0: QK/SM only, then V(0) + kT=K(1) ----
    {
        asm volatile("global_load_dwordx4 %0, %1, %2"
                     : "=v"(knx) : "v"(voffK), "s"(kb + 128 * 32));
        __builtin_amdgcn_sched_barrier(0);
        f32x4 sT[4];
        qk_and_max(sT);
        __syncthreads();                      // mx(0) visible
        sm_finish_publish(sT);
        {
            const unsigned short* sbv = vb;
            #pragma unroll
            for (int ct = 0; ct < 2; ++ct)
                #pragma unroll
                for (int kt = 0; kt < 4; ++kt)
                    asm volatile("global_load_dwordx4 %0, %1, %2"
                                 : "=v"(vA[ct][kt])
                                 : "v"(voffV[ct][kt]), "s"(sbv));
        }
        __builtin_amdgcn_sched_barrier(0);
        asm volatile("s_waitcnt vmcnt(8)" ::: "memory");   // K(1) done, 8 V in flight
        __builtin_amdgcn_sched_barrier(0);
        *reinterpret_cast<bf16x8*>(kdst) = knx;
    }

    // ---- main loop: iter jj does QK/SM(jj) + PV(jj-1) ----
    for (int jj = 1; jj < 32; ++jj) {
        __syncthreads();   // kT=K(jj), pS=P(jj-1), f/flag(jj-1) visible

        // issue K(jj+1) (clamped on last iter; harmless unused write)
        {
            const unsigned short* sbk = kb + (size_t)((jj == 31) ? 0 : (jj + 1)) * 128 * 32;
            asm volatile("global_load_dwordx4 %0, %1, %2"
                         : "=v"(knx) : "v"(voffK), "s"(sbk));
        }
        __builtin_amdgcn_sched_barrier(0);

        // QK(jj) + tile max publish
        f32x4 sT[4];
        qk_and_max(sT);

        // V(jj-1) landed (8 oldest); K(jj+1) may stay in flight
        asm volatile("s_waitcnt vmcnt(1)" ::: "memory");
        __builtin_amdgcn_sched_barrier(0);

        // rescale acc by f(jj-1) (defer-max: usually skipped)
        #pragma unroll
        for (int it = 0; it < 4; ++it) {
            if (flag_s[it]) {
                const float ff = f_s[it][li];
                acc[0][it] *= ff; acc[1][it] *= ff;
            }
        }

        // PV(jj-1): 32 MFMA
        __builtin_amdgcn_s_setprio(1);
        #pragma unroll
        for (int kt = 0; kt < 4; ++kt) {
            const bf16x8 pb0 = *reinterpret_cast<const bf16x8*>(&pS[0][kt][l * 8]);
            const bf16x8 pb1 = *reinterpret_cast<const bf16x8*>(&pS[1][kt][l * 8]);
            const bf16x8 pb2 = *reinterpret_cast<const bf16x8*>(&pS[2][kt][l * 8]);
            const bf16x8 pb3 = *reinterpret_cast<const bf16x8*>(&pS[3][kt][l * 8]);
            #pragma unroll
            for (int ct = 0; ct < 2; ++ct) {
                acc[ct][0] = __builtin_amdgcn_mfma_f32_16x16x32_bf16(vA[ct][kt], pb0, acc[ct][0], 0, 0, 0);
                acc[ct][1] = __builtin_amdgcn_mfma_f32_16x16x32_bf16(vA[ct][kt], pb1, acc[ct][1], 0, 0, 0);
                acc[ct][2] = __builtin_amdgcn_mfma_f32_16x16x32_bf16(vA[ct][kt], pb2, acc[ct][2], 0, 0, 0);
                acc[ct][3] = __builtin_amdgcn_mfma_f32_16x16x32_bf16(vA[ct][kt], pb3, acc[ct][3], 0, 0, 0);
            }
        }
        __builtin_amdgcn_s_setprio(0);

        __syncthreads();   // mx(jj) visible; pS(jj-1) fully consumed

        // softmax finish + publish pS(jj)/f(jj)/flag(jj)
        sm_finish_publish(sT);

        // issue V(jj) (vA regs free after PV above)
        {
            const unsigned short* sbv = vb + (size_t)jj * 128;
            #pragma unroll
            for (int ct = 0; ct < 2; ++ct)
                #pragma unroll
                for (int kt = 0; kt < 4; ++kt)
                    asm volatile("global_load_dwordx4 %0, %1, %2"
                                 : "=v"(vA[ct][kt])
                                 : "v"(voffV[ct][kt]), "s"(sbv));
        }
        __builtin_amdgcn_sched_barrier(0);

        // kT = K(jj+1): K done at vmcnt(8) (8 V newer, still in flight)
        asm volatile("s_waitcnt vmcnt(8)" ::: "memory");
        __builtin_amdgcn_sched_barrier(0);
        *reinterpret_cast<bf16x8*>(kdst) = knx;
    }

    // ---- epilogue: PV(31) ----
    __syncthreads();   // pS(31), f/flag(31) visible
    #pragma unroll
    for (int it = 0; it < 4; ++it) {
        if (flag_s[it]) {
            const float ff = f_s[it][li];
            acc[0][it] *= ff; acc[1][it] *= ff;
        }
    }
    asm volatile("s_waitcnt vmcnt(0)" ::: "memory");
    __builtin_amdgcn_sched_barrier(0);
    #pragma unroll
    for (int kt = 0; kt < 4; ++kt) {
        const bf16x8 pb0 = *reinterpret_cast<const bf16x8*>(&pS[0][kt][l * 8]);
        const bf16x8 pb1 = *reinterpret_cast<const bf16x8*>(&pS[1][kt][l * 8]);
        const bf16x8 pb2 = *reinterpret_cast<const bf16x8*>(&pS[2][kt][l * 8]);
        const bf16x8 pb3 = *reinterpret_cast<const bf16x8*>(&pS[3][kt][l * 8]);
        #pragma unroll
        for (int ct = 0; ct < 2; ++ct) {
            acc[ct][0] = __builtin_amdgcn_mfma_f32_16x16x32_bf16(vA[ct][kt], pb0, acc[ct][0], 0, 0, 0);
            acc[ct][1] = __builtin_amdgcn_mfma_f32_16x16x32_bf16(vA[ct][kt], pb1, acc[ct][1], 0, 0, 0);
            acc[ct][2] = __builtin_amdgcn_mfma_f32_16x16x32_bf16(vA[ct][kt], pb2, acc[ct][2], 0, 0, 0);
            acc[ct][3] = __builtin_amdgcn_mfma_f32_16x16x32_bf16(vA[ct][kt], pb3, acc[ct][3], 0, 0, 0);
        }
    }

    // ---- l: reduce over g, publish per (qslice, jhalf), sum halves ----
    float l_tot = l_part;
    l_tot += __shfl_xor(l_tot, 16);
    l_tot += __shfl_xor(l_tot, 32);
    if (l < 16) l_s[QS][JH][li] = l_tot;
    __syncthreads();

    const float gm = gamma[0];
    float linv[4];
    #pragma unroll
    for (int it = 0; it < 4; ++it)
        linv[it] = 1.0f / (l_s[it][0][li] + l_s[it][1][li]);

    const float* xb2 = x + ((size_t)b * C_) * N_;
    float* ob = out + ((size_t)b * C_) * N_;
    #pragma unroll
    for (int ct = 0; ct < 2; ++ct) {
        #pragma unroll
        for (int r = 0; r < 4; ++r) {
            const int c = cw0 + ct * 16 + 4 * g + r;
            #pragma unroll
            for (int it = 0; it < 4; ++it) {
                const int i = i0 + it * 16 + li;
                const size_t off = (size_t)c * N_ + i;
                ob[off] = gm * acc[ct][it][r] * linv[it] + xb2[off];
            }
        }
    }
}

// ---------------------------------------------------------------------------
// Workspace: q [8][4096][32] | k | v [8][256][4096] bf16 | wbf [320*256] bf16
// = 2 + 2 + 16 + 0.16 MB = ~20.2 MB in d_ws.
// ---------------------------------------------------------------------------
extern "C" void kernel_launch(void* const* d_in, const int* in_sizes, int n_in,
                              void* d_out, int out_size, void* d_ws, size_t ws_size,
                              hipStream_t stream) {
    const float* x     = (const float*)d_in[0];
    const float* Wq    = (const float*)d_in[1];
    const float* bq    = (const float*)d_in[2];
    const float* Wk    = (const float*)d_in[3];
    const float* bk    = (const float*)d_in[4];
    const float* Wv    = (const float*)d_in[5];
    const float* bv    = (const float*)d_in[6];
    const float* gamma = (const float*)d_in[7];
    float* out = (float*)d_out;

    unsigned short* q   = (unsigned short*)d_ws;
    unsigned short* k   = q + (size_t)B_ * N_ * 32;
    unsigned short* v   = k + (size_t)B_ * N_ * 32;
    unsigned short* wbf = v + (size_t)B_ * C_ * N_;

    dim3 grid(N_ / 64, B_);
    w_prep<<<80, 256, 0, stream>>>(Wq, Wk, Wv, wbf);
    qkv_proj_mfma<<<grid, 256, 0, stream>>>(x, wbf, bq, bk, bv, q, k, v);
    attn_mfma<<<512, 512, 0, stream>>>(q, k, v, x, gamma, out);
}